// Round 6
// baseline (6897.681 us; speedup 1.0000x reference)
//
#include <hip/hip_runtime.h>

// ============================================================================
// 2-layer LSTM (B=64,T=512,I=256,H=1024) + head. Persistent kernel, R6.
//
// R6 vs R5 (9.45 us/stage = SUM of weight-stream 3.2 + h-MALL 3.4 + latency
// 2.5 + LDS-conflicts 0.85):
//  * PRE-SPIN WEIGHT PREFETCH: B-frag addresses are stage-invariant -> issue
//    4 chunks of B-loads BEFORE the consumer flag spin (drain overlaps spin);
//    refill remaining chunks interleaved with MFMA. Weight stream overlaps
//    latency instead of adding.
//  * L1 PHASE SWAP: h2(n-1) part first (own-layer flag, usually ready),
//    h0(n) part second -> L0 finish latency hidden behind phase-B work.
//  * SINGLE-RTT BARRIER: one monotonic done-counter per layer (atomic add
//    after publish-drain; consumers poll the same line). 1 RTT vs 3.
//  * CONFLICT-FREE gbufT: row stride 18 (16 rows -> 16 distinct banks),
//    float2 dump stores, pointwise gather ~2-way (free).
//  * h0 FIFO 8 slots (L0 run-ahead slack).
//
// Workspace (45,359,104 B):
//   0         W0p  fp16 [32 cs][40 c][8 nt][512]   10,485,760
//   10485760  W1p  fp16 [32 cs][64 c][8 nt][512]   16,777,216
//   27262976  h0q  fp16 8 slots x [32 c][4 bg][512]  1,048,576
//   28311552  h2q  fp16 2 slots x same                 262,144
//   28573696  sync uint[2048]                            8,192
//   28581888  xpk  fp16 [512 t][8 c][4 bg][512]     16,777,216
// ============================================================================

typedef _Float16 h8 __attribute__((ext_vector_type(8)));
typedef float    f4 __attribute__((ext_vector_type(4)));
typedef float    f2 __attribute__((ext_vector_type(2)));

#define WS_W0P   0
#define WS_W1P   10485760
#define WS_H0Q   27262976
#define WS_H2Q   28311552
#define WS_SYNC  28573696
#define WS_XPK   28581888
#define WS_XPK_END 45359104ULL

static __device__ __forceinline__ float sigm(float v) { return 1.f / (1.f + __expf(-v)); }
static __device__ __forceinline__ float tanh_fast(float v) {
  const float e = __expf(2.f * v);
  return 1.f - 2.f / (e + 1.f);
}
static __device__ __forceinline__ h8 vload16(const _Float16* p) {
  return *(const volatile h8*)p;          // coherent (MALL) 16B load
}
static __device__ __forceinline__ void vstore16(_Float16* p, h8 v) {
  *(volatile h8*)p = v;                   // coherent (MALL) 16B store
}

// ---------------------------------------------------------------------------
__global__ void prep_kernel(const float* __restrict__ x,
                            const float* __restrict__ Wih0, const float* __restrict__ Whh0,
                            const float* __restrict__ Wih1, const float* __restrict__ Whh1,
                            _Float16* __restrict__ W0p, _Float16* __restrict__ W1p,
                            _Float16* __restrict__ xpk,
                            unsigned* __restrict__ hz, unsigned* __restrict__ sync_ws)
{
  const long tid0 = (long)blockIdx.x * blockDim.x + threadIdx.x;
  const long np   = (long)gridDim.x * blockDim.x;

  // W0p: e = ((cs*40 + c)*8 + nt)*512 + l15*32 + quad*8 + j
  for (long e = tid0; e < 5242880; e += np) {
    const int j = e & 7, quad = (e >> 3) & 3, l15 = (e >> 5) & 15, nt = (e >> 9) & 7;
    const int r = (int)(e >> 12);
    const int c = r % 40, cs = r / 40;
    const int col = nt * 16 + l15;
    const int row = (col >> 5) * 1024 + cs * 32 + (col & 31);
    const int k = c * 32 + quad * 8 + j;
    const float v = (k < 256) ? Wih0[(long)row * 256 + k] : Whh0[(long)row * 1024 + k - 256];
    W0p[e] = (_Float16)v;
  }
  // W1p: r = cs*64 + c
  for (long e = tid0; e < 8388608; e += np) {
    const int j = e & 7, quad = (e >> 3) & 3, l15 = (e >> 5) & 15, nt = (e >> 9) & 7;
    const int r = (int)(e >> 12);
    const int c = r & 63, cs = r >> 6;
    const int col = nt * 16 + l15;
    const int row = (col >> 5) * 1024 + cs * 32 + (col & 31);
    const int k = c * 32 + quad * 8 + j;
    const float v = (k < 1024) ? Wih1[(long)row * 1024 + k] : Whh1[(long)row * 1024 + k - 1024];
    W1p[e] = (_Float16)v;
  }
  // xpk: e = ((t*8 + c)*4 + bg)*512 + b16*32 + k32
  if (xpk) {
    for (long e = tid0; e < 8388608; e += np) {
      const int k32 = e & 31, b16 = (e >> 5) & 15, bg = (e >> 9) & 3;
      const int c = (e >> 11) & 7;
      const int t = (int)(e >> 14);
      const int b = bg * 16 + b16, k = c * 32 + k32;
      xpk[e] = (_Float16)x[(long)b * 131072 + (long)t * 256 + k];
    }
  }
  for (long e = tid0; e < 327680; e += np) hz[e] = 0u;   // h0q(8 slots) + h2q(2)
  if (tid0 < 2048) sync_ws[tid0] = 0u;
}

// ---------------------------------------------------------------------------
// sync: sy[0] = L0done, sy[16] = L1done (monotonic: 128*(stages completed))
// ---------------------------------------------------------------------------
template<bool XP>
__launch_bounds__(512, 1)
__global__ void lstm_kernel(const float* __restrict__ x, const _Float16* __restrict__ xpk,
                            const float* __restrict__ bih0, const float* __restrict__ bhh0,
                            const float* __restrict__ bih1, const float* __restrict__ bhh1,
                            const _Float16* __restrict__ W0p, const _Float16* __restrict__ W1p,
                            _Float16* __restrict__ h0q, _Float16* __restrict__ h2q,
                            unsigned* __restrict__ sy)
{
  extern __shared__ float gb[];                    // gbufT [8][128][18] = 73,728 B
  __shared__ float cst[512];                       // c-state (hh*16+b16)
  __shared__ float biasl[128];
  __shared__ _Float16 htmp[32 * 18];

  const int tid = threadIdx.x, wg = blockIdx.x;
  const int xcd = wg & 7, jdec = wg >> 3;
  const int lay = jdec & 1, jj = jdec >> 1;
  const int bg = jj & 3, csl = jj >> 2;
  const int cs = xcd * 4 + csl;                    // col-slice 0..31 (XCD-local)
  const int lane = tid & 63, kg = tid >> 6;
  const int l15 = lane & 15, quad = lane >> 4;
  const int boff = l15 * 32 + quad * 8;
  const int aoff = bg * 512 + l15 * 32 + quad * 8;

  const _Float16* Wp = lay ? (W1p + (long)cs * 262144) : (W0p + (long)cs * 163840);

  if (tid < 128) {
    const int row = (tid >> 5) * 1024 + cs * 32 + (tid & 31);
    biasl[tid] = lay ? (bih1[row] + bhh1[row]) : (bih0[row] + bhh0[row]);
  }
  cst[tid] = 0.f;
  __syncthreads();

  unsigned* const L0done = sy;
  unsigned* const L1done = sy + 16;

  auto spin_ge = [&](const unsigned* p, int target) {
    while ((int)__hip_atomic_load(p, __ATOMIC_RELAXED, __HIP_MEMORY_SCOPE_AGENT) < target)
      __builtin_amdgcn_s_sleep(2);
  };
  auto arrive = [&](unsigned* ctr) {
    __hip_atomic_fetch_add(ctr, 1u, __ATOMIC_RELAXED, __HIP_MEMORY_SCOPE_AGENT);
  };

  auto loadB = [&](h8* Bv, int c) {
    const _Float16* bp = Wp + (long)c * 4096 + boff;
#pragma unroll
    for (int nt = 0; nt < 8; ++nt) Bv[nt] = *(const h8*)(bp + nt * 512);
  };
  auto consume = [&](const h8 A, const h8* Bv, f4* acc) {
#pragma unroll
    for (int nt = 0; nt < 8; ++nt)
      acc[nt] = __builtin_amdgcn_mfma_f32_16x16x32_f16(A, Bv[nt], acc[nt], 0, 0, 0);
  };
  auto dump = [&](const f4* acc) {
#pragma unroll
    for (int nt = 0; nt < 8; ++nt) {
      const int base = (kg * 128 + nt * 16 + l15) * 18 + quad * 4;
      f2 lo = {acc[nt][0], acc[nt][1]};
      f2 hi = {acc[nt][2], acc[nt][3]};
      *(f2*)&gb[base]     = lo;
      *(f2*)&gb[base + 2] = hi;
    }
  };
  auto pointwise_publish = [&](_Float16* wr) {
    __syncthreads();                               // gbufT complete
    {
      const int b16 = tid & 15, hh = tid >> 4;
      float gv[4];
#pragma unroll
      for (int gt = 0; gt < 4; ++gt) {
        float s = biasl[gt * 32 + hh];
#pragma unroll
        for (int k = 0; k < 8; ++k) s += gb[(k * 128 + gt * 32 + hh) * 18 + b16];
        gv[gt] = s;
      }
      const float si = sigm(gv[0]), sf = sigm(gv[1]);
      const float tg = tanh_fast(gv[2]), so = sigm(gv[3]);
      const float cn = sf * cst[tid] + si * tg;
      cst[tid] = cn;
      htmp[hh * 18 + b16] = (_Float16)(so * tanh_fast(cn));
    }
    __syncthreads();
    if (tid < 64) {
      const int b16 = tid & 15, q = tid >> 4;
      union { h8 v; _Float16 e[8]; } r;
#pragma unroll
      for (int i = 0; i < 8; ++i) r.e[i] = htmp[(q * 8 + i) * 18 + b16];
      vstore16(wr + (cs * 4 + bg) * 512 + b16 * 32 + q * 8, r.v);
    }
    __syncthreads();                               // drain publish (vmcnt0)
  };

  if (lay == 0) {
    const int c0 = kg * 5;
    for (int n = 0; n < 512; ++n) {
      h8 Bq[4][8];
#pragma unroll
      for (int i = 0; i < 4; ++i) loadB(Bq[i], c0 + i);   // pre-spin prefetch
      __builtin_amdgcn_sched_barrier(0);
      if (tid == 0) { spin_ge(L0done, 128 * n); spin_ge(L1done, 128 * (n - 7)); }
      __syncthreads();

      const _Float16* h0prev = h0q + ((n - 1) & 7) * 65536;
      const _Float16* xs = XP ? (xpk + (long)n * 16384) : nullptr;
      h8 Ah[5];
#pragma unroll
      for (int i = 0; i < 5; ++i) {
        const int c = c0 + i;
        if (c < 8) {
          if (XP) Ah[i] = *(const h8*)(xs + c * 2048 + aoff);
          else {
            const float* q = x + (long)(bg * 16 + l15) * 131072 + (long)n * 256 + c * 32 + quad * 8;
            const f4 v0 = *(const f4*)q;
            const f4 v1 = *(const f4*)(q + 4);
            h8 t;
            t[0]=(_Float16)v0[0]; t[1]=(_Float16)v0[1]; t[2]=(_Float16)v0[2]; t[3]=(_Float16)v0[3];
            t[4]=(_Float16)v1[0]; t[5]=(_Float16)v1[1]; t[6]=(_Float16)v1[2]; t[7]=(_Float16)v1[3];
            Ah[i] = t;
          }
        } else {
          Ah[i] = vload16(h0prev + (c - 8) * 2048 + aoff);
        }
      }
      f4 acc[8] = {};
      consume(Ah[0], Bq[0], acc);
      loadB(Bq[0], c0 + 4);                        // chunk 4 into freed regs
      consume(Ah[1], Bq[1], acc);
      consume(Ah[2], Bq[2], acc);
      consume(Ah[3], Bq[3], acc);
      consume(Ah[4], Bq[0], acc);
      dump(acc);
      pointwise_publish(h0q + (n & 7) * 65536);
      if (tid == 0) arrive(L0done);
    }
  } else {
    const int c0 = kg * 4;
    for (int n = 0; n < 512; ++n) {
      h8 Bq[4][8];
#pragma unroll
      for (int i = 0; i < 4; ++i) loadB(Bq[i], 32 + c0 + i);  // phase-B weights
      __builtin_amdgcn_sched_barrier(0);
      if (tid == 0) spin_ge(L1done, 128 * n);      // h2(n-1) fully published
      __syncthreads();

      // phase B: h2(n-1) part (own layer, usually ready first)
      const _Float16* h2p = h2q + ((n - 1) & 1) * 65536;
      h8 Ah[4];
#pragma unroll
      for (int i = 0; i < 4; ++i) Ah[i] = vload16(h2p + (c0 + i) * 2048 + aoff);
      f4 acc[8] = {};
#pragma unroll
      for (int i = 0; i < 4; ++i) {
        consume(Ah[i], Bq[i], acc);
        loadB(Bq[i], c0 + i);                      // refill with phase-A weights
      }

      // phase A: h0(n) part
      if (tid == 0) spin_ge(L0done, 128 * (n + 1));
      __syncthreads();
      const _Float16* h0c = h0q + (n & 7) * 65536;
#pragma unroll
      for (int i = 0; i < 4; ++i) Ah[i] = vload16(h0c + (c0 + i) * 2048 + aoff);
#pragma unroll
      for (int i = 0; i < 4; ++i) consume(Ah[i], Bq[i], acc);

      dump(acc);
      pointwise_publish(h2q + (n & 1) * 65536);
      if (tid == 0) arrive(L1done);
    }
  }
}

// ---------------------------------------------------------------------------
__global__ void head_kernel(const _Float16* __restrict__ h2s, const float* __restrict__ Wh,
                            const float* __restrict__ bh, float* __restrict__ out)
{
  const int blk = blockIdx.x;            // 64*24
  const int b = blk / 24, j = blk % 24;
  const int lane = threadIdx.x;          // 64
  float sum = 0.f;
#pragma unroll
  for (int k0 = 0; k0 < 1024; k0 += 64) {
    const int hid = k0 + lane;
    const float hv = (float)h2s[((hid >> 5) * 4 + (b >> 4)) * 512 + (b & 15) * 32 + (hid & 31)];
    sum += hv * Wh[(long)j * 1024 + hid];
  }
#pragma unroll
  for (int off = 32; off > 0; off >>= 1)
    sum += __shfl_down(sum, off, 64);
  if (lane == 0) out[b * 24 + j] = sum + bh[j];
}

// ---------------------------------------------------------------------------
extern "C" void kernel_launch(void* const* d_in, const int* in_sizes, int n_in,
                              void* d_out, int out_size, void* d_ws, size_t ws_size,
                              hipStream_t stream)
{
  const float* x    = (const float*)d_in[0];
  const float* Wih0 = (const float*)d_in[1];
  const float* Whh0 = (const float*)d_in[2];
  const float* bih0 = (const float*)d_in[3];
  const float* bhh0 = (const float*)d_in[4];
  const float* Wih1 = (const float*)d_in[5];
  const float* Whh1 = (const float*)d_in[6];
  const float* bih1 = (const float*)d_in[7];
  const float* bhh1 = (const float*)d_in[8];
  const float* Whd  = (const float*)d_in[9];
  const float* bhd  = (const float*)d_in[10];

  char* ws = (char*)d_ws;
  _Float16* W0p     = (_Float16*)(ws + WS_W0P);
  _Float16* W1p     = (_Float16*)(ws + WS_W1P);
  _Float16* h0q     = (_Float16*)(ws + WS_H0Q);
  _Float16* h2q     = (_Float16*)(ws + WS_H2Q);
  unsigned* sync_ws = (unsigned*)(ws + WS_SYNC);
  float* out = (float*)d_out;

  const bool use_xpk = (ws_size >= WS_XPK_END);
  _Float16* xpk = use_xpk ? (_Float16*)(ws + WS_XPK) : nullptr;

  prep_kernel<<<dim3(2048), dim3(256), 0, stream>>>(
      x, Wih0, Whh0, Wih1, Whh1, W0p, W1p, xpk,
      (unsigned*)(ws + WS_H0Q), sync_ws);

  // static ~3.2 KB + dynamic 81,920 B LDS -> 1 WG/CU -> 256 WGs co-resident.
  if (use_xpk)
    lstm_kernel<true><<<dim3(256), dim3(512), 81920, stream>>>(
        x, xpk, bih0, bhh0, bih1, bhh1, W0p, W1p, h0q, h2q, sync_ws);
  else
    lstm_kernel<false><<<dim3(256), dim3(512), 81920, stream>>>(
        x, nullptr, bih0, bhh0, bih1, bhh1, W0p, W1p, h0q, h2q, sync_ws);

  head_kernel<<<dim3(64 * 24), dim3(64), 0, stream>>>(
      h2q + 65536, Whd, bhd, out);   // h2(511), slot 511&1 = 1
}